// Round 2
// baseline (439.605 us; speedup 1.0000x reference)
//
#include <hip/hip_runtime.h>
#include <math.h>

#define NB 8
#define CC 512
#define HH 64
#define WW 64
#define GG 16
#define GCH 32
#define OO 32   // 2*G offset rows
#define NGHW (NB * GG * HH * WW)   // 524288 elements per coord buffer

__device__ __forceinline__ float gelu_exact(float x) {
    return 0.5f * x * (1.0f + erff(x * 0.70710678118654752f));
}

// ============================================================================
// Kernel A: dwconv3x3 + LayerNorm + GELU + offset matvec -> px/py buffers
// grid (HH, NB), block 512.  Writes px to ws[0..NGHW), py to ws[NGHW..2*NGHW)
// ============================================================================
__global__ __launch_bounds__(512)
void offsets_kernel(const float* __restrict__ in_first,
                    const float* __restrict__ dw_w,
                    const float* __restrict__ dw_b,
                    const float* __restrict__ ln_g,
                    const float* __restrict__ ln_b,
                    const float* __restrict__ off_w,
                    const float* __restrict__ off_b,
                    float* __restrict__ coord_ws)
{
    const int h   = blockIdx.x;   // 0..63
    const int n   = blockIdx.y;   // 0..7
    const int tid = threadIdx.x;  // 0..511
    const int wq   = tid & 15;    // 16 quads of w
    const int cgrp = tid >> 4;    // 32 groups of 16 channels
    const int wb = wq * 4;
    const int c0 = cgrp * 16;

    __shared__ float redS [64 * 33];
    __shared__ float redS2[64 * 33];
    __shared__ float meanArr[64];
    __shared__ float rstdArr[64];
    __shared__ float offacc[64 * 33];   // [w][o]

    float xv[4][16];
    float sw [4] = {0.f, 0.f, 0.f, 0.f};
    float sw2[4] = {0.f, 0.f, 0.f, 0.f};

    // ---------- Phase A: depthwise 3x3 conv + bias ----------
    #pragma unroll 4
    for (int i = 0; i < 16; ++i) {
        const int c = c0 + i;
        float w9[9];
        #pragma unroll
        for (int k = 0; k < 9; ++k) w9[k] = dw_w[c * 9 + k];
        const float b = dw_b[c];
        float a0 = b, a1 = b, a2 = b, a3 = b;
        #pragma unroll
        for (int r = 0; r < 3; ++r) {
            const int y = h + r - 1;
            if (y < 0 || y >= HH) continue;
            const float* rowp = in_first + ((n * CC + c) * HH + y) * WW;
            const float4 m = *(const float4*)(rowp + wb);
            const float left  = (wb > 0)      ? rowp[wb - 1] : 0.0f;
            const float right = (wb + 4 < WW) ? rowp[wb + 4] : 0.0f;
            const float k0 = w9[r * 3 + 0], k1 = w9[r * 3 + 1], k2 = w9[r * 3 + 2];
            a0 += k0 * left + k1 * m.x + k2 * m.y;
            a1 += k0 * m.x  + k1 * m.y + k2 * m.z;
            a2 += k0 * m.y  + k1 * m.z + k2 * m.w;
            a3 += k0 * m.z  + k1 * m.w + k2 * right;
        }
        xv[0][i] = a0; xv[1][i] = a1; xv[2][i] = a2; xv[3][i] = a3;
        sw[0] += a0; sw2[0] += a0 * a0;
        sw[1] += a1; sw2[1] += a1 * a1;
        sw[2] += a2; sw2[2] += a2 * a2;
        sw[3] += a3; sw2[3] += a3 * a3;
    }

    // ---------- Phase B: LayerNorm stats over C per pixel ----------
    #pragma unroll
    for (int j = 0; j < 4; ++j) {
        redS [(wb + j) * 33 + cgrp] = sw[j];
        redS2[(wb + j) * 33 + cgrp] = sw2[j];
    }
    __syncthreads();
    if (tid < 64) {
        const int w = tid;
        float s = 0.f, s2 = 0.f;
        #pragma unroll 8
        for (int k = 0; k < 32; ++k) {
            s  += redS [w * 33 + k];
            s2 += redS2[w * 33 + k];
        }
        const float mu  = s * (1.0f / 512.0f);
        const float var = s2 * (1.0f / 512.0f) - mu * mu;
        meanArr[w] = mu;
        rstdArr[w] = rsqrtf(var + 1e-6f);
    }
    __syncthreads();
    for (int idx = tid; idx < 64 * 32; idx += 512) {
        offacc[(idx >> 5) * 33 + (idx & 31)] = 0.0f;
    }

    // ---------- Phase C: LN affine + exact GELU (in registers) ----------
    float mu_[4], rs_[4];
    #pragma unroll
    for (int j = 0; j < 4; ++j) { mu_[j] = meanArr[wb + j]; rs_[j] = rstdArr[wb + j]; }
    #pragma unroll 4
    for (int i = 0; i < 16; ++i) {
        const int c = c0 + i;
        const float lg = ln_g[c];
        const float lb = ln_b[c];
        #pragma unroll
        for (int j = 0; j < 4; ++j) {
            const float v = (xv[j][i] - mu_[j]) * rs_[j] * lg + lb;
            xv[j][i] = gelu_exact(v);
        }
    }
    __syncthreads();   // offacc zeroed + x1 ready

    // ---------- Phase D: offset matvec via LDS atomics ----------
    for (int o = 0; o < OO; ++o) {
        const float4* wp = (const float4*)(off_w + o * CC + c0);
        const float4 w0 = wp[0], w1 = wp[1], w2 = wp[2], w3 = wp[3];
        #pragma unroll
        for (int j = 0; j < 4; ++j) {
            const float* xj = xv[j];
            float f = w0.x * xj[0]  + w0.y * xj[1]  + w0.z * xj[2]  + w0.w * xj[3]
                    + w1.x * xj[4]  + w1.y * xj[5]  + w1.z * xj[6]  + w1.w * xj[7]
                    + w2.x * xj[8]  + w2.y * xj[9]  + w2.z * xj[10] + w2.w * xj[11]
                    + w3.x * xj[12] + w3.y * xj[13] + w3.z * xj[14] + w3.w * xj[15];
            atomicAdd(&offacc[(wb + j) * 33 + o], f);
        }
    }
    __syncthreads();

    // ---------- Phase E': emit absolute sample coords px/py ----------
    // thread layout: o = tid&31, wgroup = tid>>5 covers 4 w values
    {
        const int o   = tid & 31;
        const int wg4 = (tid >> 5) * 4;
        const int g   = o >> 1;
        const float ob = off_b[o];
        float* dst = coord_ws + (size_t)(o & 1) * NGHW
                   + (((size_t)n * GG + g) * HH + h) * WW;
        const float base = (o & 1) ? (float)h : 0.0f;  // x adds w per-element below
        #pragma unroll
        for (int j = 0; j < 4; ++j) {
            const int w = wg4 + j;
            const float wbase = (o & 1) ? base : (float)w;
            dst[w] = wbase + offacc[w * 33 + o] + ob;
        }
    }
}

// ============================================================================
// Kernel B: bilinear gather + NCHW store.
// grid (HH, NB, GG/4), block 256 (4 waves; wave = one group g, lane = w).
// ============================================================================
__global__ __launch_bounds__(256)
void sample_kernel(const float* __restrict__ in_last,
                   const float* __restrict__ coord_ws,
                   float* __restrict__ out)
{
    const int h   = blockIdx.x;
    const int n   = blockIdx.y;
    const int tid = threadIdx.x;
    const int g   = blockIdx.z * 4 + (tid >> 6);
    const int w   = tid & 63;

    const size_t cidx = (((size_t)n * GG + g) * HH + h) * WW + w;
    const float px = coord_ws[cidx];
    const float py = coord_ws[cidx + NGHW];

    const float x0f = floorf(px), y0f = floorf(py);
    const float fx = px - x0f, fy = py - y0f;
    const int x0 = (int)x0f, y0 = (int)y0f;

    float4 acc[8];
    #pragma unroll
    for (int q = 0; q < 8; ++q) acc[q] = make_float4(0.f, 0.f, 0.f, 0.f);

    #pragma unroll
    for (int t = 0; t < 4; ++t) {
        const int xi = x0 + (t & 1);
        const int yi = y0 + (t >> 1);
        const float wt = ((t & 1) ? fx : 1.0f - fx) * ((t >> 1) ? fy : 1.0f - fy);
        if (xi >= 0 && xi < WW && yi >= 0 && yi < HH) {
            const float4* bp = (const float4*)(in_last + (((size_t)n * HH + yi) * WW + xi) * CC + g * GCH);
            #pragma unroll
            for (int q = 0; q < 8; ++q) {
                const float4 v = bp[q];
                acc[q].x += wt * v.x;
                acc[q].y += wt * v.y;
                acc[q].z += wt * v.z;
                acc[q].w += wt * v.w;
            }
        }
    }

    // Full-row stores: all 64 lanes (= all w) write one contiguous 256 B row
    float* op = out + (((size_t)n * CC + g * GCH) * HH + h) * WW + w;
    #pragma unroll
    for (int q = 0; q < 8; ++q) {
        op[(4 * q + 0) * (HH * WW)] = acc[q].x;
        op[(4 * q + 1) * (HH * WW)] = acc[q].y;
        op[(4 * q + 2) * (HH * WW)] = acc[q].z;
        op[(4 * q + 3) * (HH * WW)] = acc[q].w;
    }
}

extern "C" void kernel_launch(void* const* d_in, const int* in_sizes, int n_in,
                              void* d_out, int out_size, void* d_ws, size_t ws_size,
                              hipStream_t stream) {
    const float* in_first = (const float*)d_in[0];
    const float* in_last  = (const float*)d_in[1];
    const float* dw_w     = (const float*)d_in[2];
    const float* dw_b     = (const float*)d_in[3];
    const float* ln_g     = (const float*)d_in[4];
    const float* ln_b     = (const float*)d_in[5];
    const float* off_w    = (const float*)d_in[6];
    const float* off_b    = (const float*)d_in[7];
    float* out      = (float*)d_out;
    float* coord_ws = (float*)d_ws;   // needs 2*NGHW*4 = 4 MiB

    dim3 gridA(HH, NB);
    offsets_kernel<<<gridA, 512, 0, stream>>>(in_first, dw_w, dw_b, ln_g, ln_b,
                                              off_w, off_b, coord_ws);

    dim3 gridB(HH, NB, GG / 4);
    sample_kernel<<<gridB, 256, 0, stream>>>(in_last, coord_ws, out);
}

// Round 3
// 309.643 us; speedup vs baseline: 1.4197x; 1.4197x over previous
//
#include <hip/hip_runtime.h>
#include <math.h>

#define NB 8
#define CC 512
#define HH 64
#define WW 64
#define GG 16
#define GCH 32
#define OO 32   // 2*G offset rows
#define NGHW (NB * GG * HH * WW)   // 524288 elements per coord buffer

__device__ __forceinline__ float gelu_exact(float x) {
    return 0.5f * x * (1.0f + erff(x * 0.70710678118654752f));
}

// ============================================================================
// Kernel A: dwconv3x3 + LayerNorm + GELU + offset matvec -> px/py buffers
// grid (HH, NB), block 512.  __launch_bounds__(512,2): VGPR cap 256 so the
// 64-float xv[] array stays in registers (56-VGPR build spilled -> 132 MB of
// scratch writes, the round-2 bottleneck).
// ============================================================================
__global__ __launch_bounds__(512, 2)
void offsets_kernel(const float* __restrict__ in_first,
                    const float* __restrict__ dw_w,
                    const float* __restrict__ dw_b,
                    const float* __restrict__ ln_g,
                    const float* __restrict__ ln_b,
                    const float* __restrict__ off_w,
                    const float* __restrict__ off_b,
                    float* __restrict__ coord_ws)
{
    const int h   = blockIdx.x;   // 0..63
    const int n   = blockIdx.y;   // 0..7
    const int tid = threadIdx.x;  // 0..511
    const int wq   = tid & 15;    // 16 quads of w
    const int cgrp = tid >> 4;    // 32 groups of 16 channels
    const int wb = wq * 4;
    const int c0 = cgrp * 16;

    __shared__ float redS [64 * 33];
    __shared__ float redS2[64 * 33];
    __shared__ float meanArr[64];
    __shared__ float rstdArr[64];
    __shared__ float offacc[64 * 33];   // [w][o]

    float xv[4][16];
    float sw [4] = {0.f, 0.f, 0.f, 0.f};
    float sw2[4] = {0.f, 0.f, 0.f, 0.f};

    // ---------- Phase A: depthwise 3x3 conv + bias ----------
    // halo (left/right) comes from the neighbor lane's float4 via shfl, not
    // scalar loads: wq-1 / wq+1 are lane-1 / lane+1 within the wave.
    #pragma unroll 4
    for (int i = 0; i < 16; ++i) {
        const int c = c0 + i;
        float w9[9];
        #pragma unroll
        for (int k = 0; k < 9; ++k) w9[k] = dw_w[c * 9 + k];
        const float b = dw_b[c];
        float a0 = b, a1 = b, a2 = b, a3 = b;
        #pragma unroll
        for (int r = 0; r < 3; ++r) {
            const int y = h + r - 1;
            if (y < 0 || y >= HH) continue;
            const float* rowp = in_first + ((n * CC + c) * HH + y) * WW;
            const float4 m = *(const float4*)(rowp + wb);
            float left  = __shfl_up(m.w, 1);
            float right = __shfl_down(m.x, 1);
            if (wq == 0)  left  = 0.0f;   // wb==0 -> w=-1 pad
            if (wq == 15) right = 0.0f;   // wb+4==64 -> pad
            const float k0 = w9[r * 3 + 0], k1 = w9[r * 3 + 1], k2 = w9[r * 3 + 2];
            a0 += k0 * left + k1 * m.x + k2 * m.y;
            a1 += k0 * m.x  + k1 * m.y + k2 * m.z;
            a2 += k0 * m.y  + k1 * m.z + k2 * m.w;
            a3 += k0 * m.z  + k1 * m.w + k2 * right;
        }
        xv[0][i] = a0; xv[1][i] = a1; xv[2][i] = a2; xv[3][i] = a3;
        sw[0] += a0; sw2[0] += a0 * a0;
        sw[1] += a1; sw2[1] += a1 * a1;
        sw[2] += a2; sw2[2] += a2 * a2;
        sw[3] += a3; sw2[3] += a3 * a3;
    }

    // ---------- Phase B: LayerNorm stats over C per pixel ----------
    #pragma unroll
    for (int j = 0; j < 4; ++j) {
        redS [(wb + j) * 33 + cgrp] = sw[j];
        redS2[(wb + j) * 33 + cgrp] = sw2[j];
    }
    __syncthreads();
    if (tid < 64) {
        const int w = tid;
        float s = 0.f, s2 = 0.f;
        #pragma unroll 8
        for (int k = 0; k < 32; ++k) {
            s  += redS [w * 33 + k];
            s2 += redS2[w * 33 + k];
        }
        const float mu  = s * (1.0f / 512.0f);
        const float var = s2 * (1.0f / 512.0f) - mu * mu;
        meanArr[w] = mu;
        rstdArr[w] = rsqrtf(var + 1e-6f);
    }
    __syncthreads();
    for (int idx = tid; idx < 64 * 32; idx += 512) {
        offacc[(idx >> 5) * 33 + (idx & 31)] = 0.0f;
    }

    // ---------- Phase C: LN affine + exact GELU (in registers) ----------
    float mu_[4], rs_[4];
    #pragma unroll
    for (int j = 0; j < 4; ++j) { mu_[j] = meanArr[wb + j]; rs_[j] = rstdArr[wb + j]; }
    #pragma unroll 4
    for (int i = 0; i < 16; ++i) {
        const int c = c0 + i;
        const float lg = ln_g[c];
        const float lb = ln_b[c];
        #pragma unroll
        for (int j = 0; j < 4; ++j) {
            const float v = (xv[j][i] - mu_[j]) * rs_[j] * lg + lb;
            xv[j][i] = gelu_exact(v);
        }
    }
    __syncthreads();   // offacc zeroed + x1 ready

    // ---------- Phase D: offset matvec ----------
    // In-wave pre-reduction over the 4 cgrp lanes sharing each wq (lane,
    // lane+16, lane+32, lane+48), then one LDS atomic per 8 waves.
    const int lane = tid & 63;
    for (int o = 0; o < OO; ++o) {
        const float4* wp = (const float4*)(off_w + o * CC + c0);
        const float4 w0 = wp[0], w1 = wp[1], w2 = wp[2], w3 = wp[3];
        #pragma unroll
        for (int j = 0; j < 4; ++j) {
            const float* xj = xv[j];
            float f = w0.x * xj[0]  + w0.y * xj[1]  + w0.z * xj[2]  + w0.w * xj[3]
                    + w1.x * xj[4]  + w1.y * xj[5]  + w1.z * xj[6]  + w1.w * xj[7]
                    + w2.x * xj[8]  + w2.y * xj[9]  + w2.z * xj[10] + w2.w * xj[11]
                    + w3.x * xj[12] + w3.y * xj[13] + w3.z * xj[14] + w3.w * xj[15];
            f += __shfl_down(f, 32);
            f += __shfl_down(f, 16);
            if (lane < 16)
                atomicAdd(&offacc[(wb + j) * 33 + o], f);
        }
    }
    __syncthreads();

    // ---------- Phase E: emit absolute sample coords px/py ----------
    {
        const int o   = tid & 31;
        const int wg4 = (tid >> 5) * 4;
        const int g   = o >> 1;
        const float ob = off_b[o];
        float* dst = coord_ws + (size_t)(o & 1) * NGHW
                   + (((size_t)n * GG + g) * HH + h) * WW;
        #pragma unroll
        for (int j = 0; j < 4; ++j) {
            const int w = wg4 + j;
            const float wbase = (o & 1) ? (float)h : (float)w;
            dst[w] = wbase + offacc[w * 33 + o] + ob;
        }
    }
}

// ============================================================================
// Kernel B: bilinear gather + LDS transpose + coalesced NCHW store.
// grid (HH, NB, GG), block 256.  Gather: lanes span channels (8 x float4 =
// 128 B contiguous per tap).  Store: lanes span w (256 B contiguous rows).
// ============================================================================
__global__ __launch_bounds__(256)
void sample_kernel(const float* __restrict__ in_last,
                   const float* __restrict__ coord_ws,
                   float* __restrict__ out)
{
    const int h   = blockIdx.x;
    const int n   = blockIdx.y;
    const int g   = blockIdx.z;
    const int tid = threadIdx.x;

    __shared__ float pxs[64];
    __shared__ float pys[64];
    __shared__ float smem[64 * 33];   // [w][c], stride 33: conflict-free both phases

    if (tid < 128) {
        const int w = tid & 63;
        const size_t cidx = (((size_t)n * GG + g) * HH + h) * WW + w;
        if (tid < 64) pxs[w] = coord_ws[cidx];
        else          pys[w] = coord_ws[cidx + NGHW];
    }
    __syncthreads();

    // gather: thread = (c4 = tid&7  -> float4 within the 32-ch group,
    //                   wslot = tid>>3 -> w; two passes cover 64 w)
    const int c4    = tid & 7;
    const int wslot = tid >> 3;
    const float* base = in_last + (size_t)n * HH * WW * CC + g * GCH + c4 * 4;

    #pragma unroll
    for (int pass = 0; pass < 2; ++pass) {
        const int w = wslot + pass * 32;
        const float px = pxs[w];
        const float py = pys[w];
        const float x0f = floorf(px), y0f = floorf(py);
        const float fx = px - x0f, fy = py - y0f;
        const int x0 = (int)x0f, y0 = (int)y0f;

        float4 acc = make_float4(0.f, 0.f, 0.f, 0.f);
        #pragma unroll
        for (int t = 0; t < 4; ++t) {
            const int xi = x0 + (t & 1);
            const int yi = y0 + (t >> 1);
            const float wt = ((t & 1) ? fx : 1.0f - fx) * ((t >> 1) ? fy : 1.0f - fy);
            if (xi >= 0 && xi < WW && yi >= 0 && yi < HH) {
                const float4 v = *(const float4*)(base + ((size_t)yi * WW + xi) * CC);
                acc.x += wt * v.x;
                acc.y += wt * v.y;
                acc.z += wt * v.z;
                acc.w += wt * v.w;
            }
        }
        float* sp = smem + w * 33 + c4 * 4;
        sp[0] = acc.x; sp[1] = acc.y; sp[2] = acc.z; sp[3] = acc.w;
    }
    __syncthreads();

    // store: thread = (c = tid>>6 (+4/pass), w = tid&63); full 256 B rows
    const int w  = tid & 63;
    const int cb = tid >> 6;
    float* op = out + (((size_t)n * CC + g * GCH) * HH + h) * WW + w;
    #pragma unroll
    for (int pass = 0; pass < 8; ++pass) {
        const int c = pass * 4 + cb;
        op[(size_t)c * (HH * WW)] = smem[w * 33 + c];
    }
}

extern "C" void kernel_launch(void* const* d_in, const int* in_sizes, int n_in,
                              void* d_out, int out_size, void* d_ws, size_t ws_size,
                              hipStream_t stream) {
    const float* in_first = (const float*)d_in[0];
    const float* in_last  = (const float*)d_in[1];
    const float* dw_w     = (const float*)d_in[2];
    const float* dw_b     = (const float*)d_in[3];
    const float* ln_g     = (const float*)d_in[4];
    const float* ln_b     = (const float*)d_in[5];
    const float* off_w    = (const float*)d_in[6];
    const float* off_b    = (const float*)d_in[7];
    float* out      = (float*)d_out;
    float* coord_ws = (float*)d_ws;   // 2*NGHW*4 = 4 MiB

    dim3 gridA(HH, NB);
    offsets_kernel<<<gridA, 512, 0, stream>>>(in_first, dw_w, dw_b, ln_g, ln_b,
                                              off_w, off_b, coord_ws);

    dim3 gridB(HH, NB, GG);
    sample_kernel<<<gridB, 256, 0, stream>>>(in_last, coord_ws, out);
}